// Round 1
// baseline (1580.353 us; speedup 1.0000x reference)
//
#include <hip/hip_runtime.h>

#define BB   4096
#define TT   2048
#define DDIM 3
#define SDIM 5
#define HDIM 32

// ds_swizzle XOR butterfly within 32-lane groups (BitMode: offset = xor<<10 | or<<5 | and)
template<int MASK>
__device__ __forceinline__ float swz_xor(float v) {
    return __int_as_float(
        __builtin_amdgcn_ds_swizzle(__float_as_int(v), (MASK << 10) | 0x1F));
}

__device__ __forceinline__ float fast_tanh(float x) {
    // tanh(x) = 1 - 2/(1+exp(2x)); saturates correctly for |x| large (exp->inf/0)
    float e = __expf(2.0f * x);                      // v_mul + v_exp_f32
    float r = __builtin_amdgcn_rcpf(e + 1.0f);       // v_rcp_f32
    return fmaf(-2.0f, r, 1.0f);
}

__global__ __launch_bounds__(64, 2) void msc_scan_kernel(
    const float* __restrict__ delta, const float* __restrict__ state0,
    const float* __restrict__ W1, const float* __restrict__ b1,
    const float* __restrict__ W2, const float* __restrict__ b2,
    const float* __restrict__ W3, const float* __restrict__ b3,
    float* __restrict__ out)
{
    __shared__ __align__(16) float h1buf[2][HDIM];   // one 32-float buffer per 32-lane group

    const int tid = threadIdx.x;
    const int grp = tid >> 5;        // 0 or 1: which batch chain in this wave
    const int j   = tid & 31;        // hidden unit owned by this lane
    const int b   = blockIdx.x * 2 + grp;

    // ---- weights into registers (lane j needs: W1 col j, W2 col j, W3 row j) ----
    float w1c[8], w2c[32], w3c[5];
    #pragma unroll
    for (int i = 0; i < 8; ++i)  w1c[i] = W1[i * HDIM + j];
    #pragma unroll
    for (int i = 0; i < 32; ++i) w2c[i] = W2[i * HDIM + j];
    #pragma unroll
    for (int s = 0; s < 5; ++s)  w3c[s] = W3[j * SDIM + s];
    const float b1j = b1[j];
    const float b2j = b2[j];
    float b3l[5];
    #pragma unroll
    for (int s = 0; s < 5; ++s)  b3l[s] = (j == 0) ? b3[s] : 0.0f;   // bias folded into lane-0 partial

    // ---- state replicated across the 32 lanes of the group ----
    float s0 = state0[b * SDIM + 0];
    float s1 = state0[b * SDIM + 1];
    float s2 = state0[b * SDIM + 2];
    float s3 = state0[b * SDIM + 3];
    float s4 = state0[b * SDIM + 4];

    const float* dp = delta + (size_t)b * TT * DDIM;
    float*       op = out   + (size_t)b * TT * SDIM;

    // prefetch t=0 delta (group-uniform addresses -> broadcast loads)
    float d0n = dp[0], d1n = dp[1], d2n = dp[2];

    const float4* h4 = reinterpret_cast<const float4*>(&h1buf[grp][0]);

    for (int t = 0; t < TT; ++t) {
        float d0 = d0n, d1 = d1n, d2 = d2n;
        if (t + 1 < TT) {                       // software prefetch next step's delta
            const float* p = dp + (size_t)(t + 1) * DDIM;
            d0n = p[0]; d1n = p[1]; d2n = p[2];
        }

        // ---- layer 1: h1[j] = tanh(x @ W1 + b1), x = [state(5), delta(3)] ----
        float a = fmaf(s0, w1c[0], b1j);
        a = fmaf(s1, w1c[1], a);
        a = fmaf(s2, w1c[2], a);
        a = fmaf(s3, w1c[3], a);
        a = fmaf(s4, w1c[4], a);
        a = fmaf(d0, w1c[5], a);
        a = fmaf(d1, w1c[6], a);
        a = fmaf(d2, w1c[7], a);
        float h1 = fast_tanh(a);

        // ---- broadcast h1 across the group via LDS (in-order DS pipe within wave) ----
        h1buf[grp][j] = h1;
        __builtin_amdgcn_wave_barrier();
        float4 q[8];
        #pragma unroll
        for (int i = 0; i < 8; ++i) q[i] = h4[i];   // 8x ds_read_b128, broadcast (conflict-free)
        __builtin_amdgcn_wave_barrier();

        // ---- layer 2: h2[j] = tanh(h1 @ W2 + b2), 4 independent FMA chains ----
        float a0 = b2j, a1 = 0.f, a2 = 0.f, a3 = 0.f;
        #pragma unroll
        for (int i = 0; i < 8; ++i) {
            a0 = fmaf(q[i].x, w2c[4*i + 0], a0);
            a1 = fmaf(q[i].y, w2c[4*i + 1], a1);
            a2 = fmaf(q[i].z, w2c[4*i + 2], a2);
            a3 = fmaf(q[i].w, w2c[4*i + 3], a3);
        }
        float h2 = fast_tanh((a0 + a1) + (a2 + a3));

        // ---- layer 3: state[s] += sum_j h2[j]*W3[j][s] + b3[s] ----
        float p0 = fmaf(h2, w3c[0], b3l[0]);
        float p1 = fmaf(h2, w3c[1], b3l[1]);
        float p2 = fmaf(h2, w3c[2], b3l[2]);
        float p3 = fmaf(h2, w3c[3], b3l[3]);
        float p4 = fmaf(h2, w3c[4], b3l[4]);
        // butterfly reduce+broadcast over the 32-lane group
        p0 += swz_xor<1>(p0); p0 += swz_xor<2>(p0); p0 += swz_xor<4>(p0); p0 += swz_xor<8>(p0); p0 += swz_xor<16>(p0);
        p1 += swz_xor<1>(p1); p1 += swz_xor<2>(p1); p1 += swz_xor<4>(p1); p1 += swz_xor<8>(p1); p1 += swz_xor<16>(p1);
        p2 += swz_xor<1>(p2); p2 += swz_xor<2>(p2); p2 += swz_xor<4>(p2); p2 += swz_xor<8>(p2); p2 += swz_xor<16>(p2);
        p3 += swz_xor<1>(p3); p3 += swz_xor<2>(p3); p3 += swz_xor<4>(p3); p3 += swz_xor<8>(p3); p3 += swz_xor<16>(p3);
        p4 += swz_xor<1>(p4); p4 += swz_xor<2>(p4); p4 += swz_xor<4>(p4); p4 += swz_xor<8>(p4); p4 += swz_xor<16>(p4);

        s0 += p0; s1 += p1; s2 += p2; s3 += p3; s4 += p4;

        // ---- store new_state (lanes 0..4 of each group) ----
        float sv = (j == 1) ? s1 : s0;
        sv = (j == 2) ? s2 : sv;
        sv = (j == 3) ? s3 : sv;
        sv = (j == 4) ? s4 : sv;
        if (j < SDIM) op[t * SDIM + j] = sv;
    }
}

extern "C" void kernel_launch(void* const* d_in, const int* in_sizes, int n_in,
                              void* d_out, int out_size, void* d_ws, size_t ws_size,
                              hipStream_t stream) {
    const float* delta  = (const float*)d_in[0];
    const float* state0 = (const float*)d_in[1];
    const float* W1     = (const float*)d_in[2];
    const float* b1     = (const float*)d_in[3];
    const float* W2     = (const float*)d_in[4];
    const float* b2     = (const float*)d_in[5];
    const float* W3     = (const float*)d_in[6];
    const float* b3     = (const float*)d_in[7];
    float* out = (float*)d_out;

    msc_scan_kernel<<<dim3(BB / 2), dim3(64), 0, stream>>>(
        delta, state0, W1, b1, W2, b2, W3, b3, out);
}

// Round 4
// 1244.419 us; speedup vs baseline: 1.2700x; 1.2700x over previous
//
#include <hip/hip_runtime.h>

#define BB   4096
#define TT   2048
#define DDIM 3
#define SDIM 5
#define HDIM 32

// ds_swizzle lane^16 within each 32-lane half (BitMode: xor<<10 | and 0x1F)
__device__ __forceinline__ float swz_xor16(float v) {
    return __int_as_float(
        __builtin_amdgcn_ds_swizzle(__float_as_int(v), (16 << 10) | 0x1F));
}

// DPP move with compile-time control (full row/bank masks, all lanes valid)
template<int CTRL>
__device__ __forceinline__ float dpp_mov(float v) {
    return __int_as_float(
        __builtin_amdgcn_update_dpp(0, __float_as_int(v), CTRL, 0xF, 0xF, true));
}

#define DPP_ROW_MIRROR 0x140  /* lane ^ 15 within 16 */
#define DPP_HALF_MIRROR 0x141 /* lane ^ 7 within 8   */
#define DPP_QUAD_XOR2  0x4E   /* quad_perm [2,3,0,1] = lane ^ 2 */
#define DPP_QUAD_XOR1  0xB1   /* quad_perm [1,0,3,2] = lane ^ 1 */
#define DPP_ROR8  0x128
#define DPP_ROR4  0x124
#define DPP_ROR2  0x122
#define DPP_ROR1  0x121

#if __has_builtin(__builtin_amdgcn_exp2f)
__device__ __forceinline__ float fexp2(float x) { return __builtin_amdgcn_exp2f(x); }
#else
__device__ __forceinline__ float fexp2(float x) { return exp2f(x); }
#endif

// input pre-scaled by 2*log2(e):  tanh = 1 - 2/(1 + 2^a)
__device__ __forceinline__ float tanh_pre(float a) {
    return fmaf(-2.0f, __builtin_amdgcn_rcpf(1.0f + fexp2(a)), 1.0f);
}

__global__ __launch_bounds__(64, 2) void msc_scan_kernel(
    const float* __restrict__ delta, const float* __restrict__ state0,
    const float* __restrict__ W1, const float* __restrict__ b1,
    const float* __restrict__ W2, const float* __restrict__ b2,
    const float* __restrict__ W3, const float* __restrict__ b3,
    float* __restrict__ out)
{
    const int tid = threadIdx.x;
    const int j   = tid & 31;                 // hidden unit owned by this lane
    const int b   = blockIdx.x * 2 + (tid >> 5);

    const float K = 2.885390081777926815f;    // 2*log2(e), folded for exp2-tanh

    // ---- weights into registers ----
    float w1c[8];
    #pragma unroll
    for (int i = 0; i < 8; ++i)  w1c[i] = K * W1[i * HDIM + j];
    const float b1j = K * b1[j];

    // gather-tree slot m holds h1[j ^ mask(m)]; permute W2 rows to match.
    // mask bits: slot bit0 -> ^16 (swizzle), bit1 -> ^15 (row mirror),
    //            bit2 -> ^7 (half mirror), bit3 -> ^2, bit4 -> ^1 (quad perms)
    float w2c[32];
    #pragma unroll
    for (int s = 0; s < 32; ++s) {
        int m = ((s & 1) ? 16 : 0) ^ ((s & 2) ? 15 : 0) ^ ((s & 4) ? 7 : 0)
              ^ ((s & 8) ? 2 : 0) ^ ((s & 16) ? 1 : 0);
        w2c[s] = K * W2[(j ^ m) * HDIM + j];
    }
    const float b2j = K * b2[j];

    float w3c[5], b3l[5];
    #pragma unroll
    for (int s = 0; s < 5; ++s) {
        w3c[s] = W3[j * SDIM + s];
        b3l[s] = (j == 0) ? b3[s] : 0.0f;     // bias enters reduce once, via lane 0
    }

    float st[5];
    #pragma unroll
    for (int s = 0; s < 5; ++s) st[s] = state0[b * SDIM + s];

    const float4* dp4 = reinterpret_cast<const float4*>(delta + (size_t)b * TT * DDIM);
    float*        op  = out + (size_t)b * TT * SDIM;

    auto step = [&](float d0, float d1, float d2, int t) {
        // ---- layer 1 (two chains + combine) ----
        float a = fmaf(st[0], w1c[0], b1j);
        a = fmaf(st[1], w1c[1], a);
        a = fmaf(st[2], w1c[2], a);
        a = fmaf(st[3], w1c[3], a);
        float c = st[4] * w1c[4];
        c = fmaf(d0, w1c[5], c);
        c = fmaf(d1, w1c[6], c);
        c = fmaf(d2, w1c[7], c);
        float h1 = tanh_pre(a + c);

        // ---- all-gather of h1 across the 32-lane group: 1 swizzle + 30 DPP ----
        float v[32];
        v[0] = h1;
        v[1] = swz_xor16(v[0]);
        #pragma unroll
        for (int m = 0; m < 2; ++m)  v[2 + m]  = dpp_mov<DPP_ROW_MIRROR>(v[m]);
        #pragma unroll
        for (int m = 0; m < 4; ++m)  v[4 + m]  = dpp_mov<DPP_HALF_MIRROR>(v[m]);
        #pragma unroll
        for (int m = 0; m < 8; ++m)  v[8 + m]  = dpp_mov<DPP_QUAD_XOR2>(v[m]);
        #pragma unroll
        for (int m = 0; m < 16; ++m) v[16 + m] = dpp_mov<DPP_QUAD_XOR1>(v[m]);

        // ---- layer 2: 4 independent FMA chains over permuted weights ----
        float a0 = b2j, a1 = 0.f, a2 = 0.f, a3 = 0.f;
        #pragma unroll
        for (int m = 0; m < 8; ++m) {
            a0 = fmaf(v[4*m + 0], w2c[4*m + 0], a0);
            a1 = fmaf(v[4*m + 1], w2c[4*m + 1], a1);
            a2 = fmaf(v[4*m + 2], w2c[4*m + 2], a2);
            a3 = fmaf(v[4*m + 3], w2c[4*m + 3], a3);
        }
        float h2 = tanh_pre((a0 + a1) + (a2 + a3));

        // ---- layer 3 + all-reduce: 4 DPP ror-adds + 1 swizzle per state dim ----
        #pragma unroll
        for (int s = 0; s < 5; ++s) {
            float q = fmaf(h2, w3c[s], b3l[s]);
            q += dpp_mov<DPP_ROR8>(q);
            q += dpp_mov<DPP_ROR4>(q);
            q += dpp_mov<DPP_ROR2>(q);
            q += dpp_mov<DPP_ROR1>(q);
            q += swz_xor16(q);
            st[s] += q;
        }

        // ---- store new_state (lanes 0..4) ----
        float sv = st[0];
        sv = (j == 1) ? st[1] : sv;
        sv = (j == 2) ? st[2] : sv;
        sv = (j == 3) ? st[3] : sv;
        sv = (j == 4) ? st[4] : sv;
        if (j < SDIM) op[(size_t)t * SDIM + j] = sv;
    };

    // ---- main loop: 4 steps per iteration, delta as 3x float4, 1 group ahead ----
    float4 c0 = dp4[0], c1 = dp4[1], c2 = dp4[2];
    for (int t4 = 0; t4 < TT / 4; ++t4) {
        const int tn = (t4 + 1 < TT / 4) ? (t4 + 1) : t4;
        float4 n0 = dp4[tn * 3 + 0];
        float4 n1 = dp4[tn * 3 + 1];
        float4 n2 = dp4[tn * 3 + 2];

        step(c0.x, c0.y, c0.z, 4 * t4 + 0);
        step(c0.w, c1.x, c1.y, 4 * t4 + 1);
        step(c1.z, c1.w, c2.x, 4 * t4 + 2);
        step(c2.y, c2.z, c2.w, 4 * t4 + 3);

        c0 = n0; c1 = n1; c2 = n2;
    }
}

extern "C" void kernel_launch(void* const* d_in, const int* in_sizes, int n_in,
                              void* d_out, int out_size, void* d_ws, size_t ws_size,
                              hipStream_t stream) {
    const float* delta  = (const float*)d_in[0];
    const float* state0 = (const float*)d_in[1];
    const float* W1     = (const float*)d_in[2];
    const float* b1     = (const float*)d_in[3];
    const float* W2     = (const float*)d_in[4];
    const float* b2     = (const float*)d_in[5];
    const float* W3     = (const float*)d_in[6];
    const float* b3     = (const float*)d_in[7];
    float* out = (float*)d_out;

    msc_scan_kernel<<<dim3(BB / 2), dim3(64), 0, stream>>>(
        delta, state0, W1, b1, W2, b2, W3, b3, out);
}